// Round 1
// baseline (138.400 us; speedup 1.0000x reference)
//
#include <hip/hip_runtime.h>
#include <hip/hip_bf16.h>
#include <math.h>

// Problem constants
#define B_    2
#define K_    8
#define C_    64
#define CH_   32      // C/2
#define H_    128
#define W_    128
#define HW_   16384   // H*W
#define BN_EPS 1e-5f
#define SIGMA_MAX 0.3f
#define COV_SHRINK 0.1f
#define COV_DELTA 1e-3f

// ---------------------------------------------------------------------------
// Kernel 0: fold BN into w1 (transposed for contiguous scalar loads), copy w2,
// compute softmax(a0_raw) and sigma^2. Params layout in ws (floats):
//   [0..2047]     wf_t[c][o] = w1[o][c] * bn_scale[o]/sqrt(var[o]+eps)   (64 x 32)
//   [2048..2079]  beff[o]    = bn_bias[o] - bn_mean[o]*inv_std[o]
//   [2080..2111]  w2[o]
//   [2112..2119]  a0[k]      = softmax(a0_raw)[k]
//   [2120..2127]  sig2[k]    = (SIGMA_MAX*sigmoid(sigma_raw[k]))^2
// ---------------------------------------------------------------------------
__global__ void prep_kernel(const float* __restrict__ w1,
                            const float* __restrict__ bn_scale,
                            const float* __restrict__ bn_bias,
                            const float* __restrict__ bn_mean,
                            const float* __restrict__ bn_var,
                            const float* __restrict__ w2,
                            const float* __restrict__ a0_raw,
                            const float* __restrict__ sigma_raw,
                            float* __restrict__ par) {
    int t = threadIdx.x;
    for (int i = t; i < CH_ * C_; i += blockDim.x) {
        int c = i >> 5;         // 0..63
        int o = i & 31;         // 0..31
        float inv = bn_scale[o] / sqrtf(bn_var[o] + BN_EPS);
        par[c * CH_ + o] = w1[o * C_ + c] * inv;
    }
    if (t < CH_) {
        float inv = bn_scale[t] / sqrtf(bn_var[t] + BN_EPS);
        par[2048 + t] = bn_bias[t] - bn_mean[t] * inv;
        par[2080 + t] = w2[t];
    }
    if (t < K_) {
        float m = -1e30f;
        for (int i = 0; i < K_; ++i) m = fmaxf(m, a0_raw[i]);
        float s = 0.f;
        for (int i = 0; i < K_; ++i) s += expf(a0_raw[i] - m);
        par[2112 + t] = expf(a0_raw[t] - m) / s;
        float sg = SIGMA_MAX / (1.f + expf(-sigma_raw[t]));
        par[2120 + t] = sg * sg;
    }
}

// ---------------------------------------------------------------------------
// Kernel 1: sensor maps. One thread per (b,k,h,w).
// S[bk][hw] = sum_o w2[o] * relu( sum_c wf_t[c][o]*x[c] + beff[o] )
// Weights indexed wave-uniformly -> compiler emits scalar loads (SGPR
// operands into v_fmac), keeping the VALU free for the 2048 FMAs/thread.
// ---------------------------------------------------------------------------
__global__ void __launch_bounds__(256)
stage1_kernel(const float* __restrict__ X,
              const float* __restrict__ wf,    // [64][32]
              const float* __restrict__ beff,  // [32]
              const float* __restrict__ w2,    // [32]
              float* __restrict__ S) {
    int idx = blockIdx.x * blockDim.x + threadIdx.x;   // 0 .. B*K*HW-1
    int hw = idx & (HW_ - 1);
    int bk = idx >> 14;
    const float* xp = X + (size_t)bk * (C_ * HW_) + hw;

    float acc[CH_];
#pragma unroll
    for (int o = 0; o < CH_; ++o) acc[o] = beff[o];

#pragma unroll 4
    for (int c = 0; c < C_; ++c) {
        float xv = xp[(size_t)c * HW_];
        const float* wrow = wf + c * CH_;
#pragma unroll
        for (int o = 0; o < CH_; ++o) acc[o] = fmaf(wrow[o], xv, acc[o]);
    }
    float s = 0.f;
#pragma unroll
    for (int o = 0; o < CH_; ++o) s = fmaf(w2[o], fmaxf(acc[o], 0.f), s);
    S[idx] = s;
}

// ---------------------------------------------------------------------------
// Kernel 2: per-pixel 3x3 reflect patches -> 8x8 covariance -> diagonal-loaded
// SPD solve (Cholesky) -> normalized weights w[pix][k]. One thread per pixel.
// ---------------------------------------------------------------------------
__global__ void capon_kernel(const float* __restrict__ S,
                             const float* __restrict__ a0,    // [8]
                             const float* __restrict__ sig2,  // [8]
                             float* __restrict__ wOut) {      // [B*HW][8]
    int idx = blockIdx.x * blockDim.x + threadIdx.x;  // 0 .. B*HW-1
    int b  = idx >> 14;
    int hw = idx & (HW_ - 1);
    int h  = hw >> 7;
    int w  = hw & (W_ - 1);

    // reflect padding (np.pad 'reflect': -1 -> 1, H -> H-2)
    int hm = (h == 0)      ? 1       : h - 1;
    int hp = (h == H_ - 1) ? H_ - 2  : h + 1;
    int wm = (w == 0)      ? 1       : w - 1;
    int wp = (w == W_ - 1) ? W_ - 2  : w + 1;
    int row0 = hm * W_, row1 = h * W_, row2 = hp * W_;
    int rows[3] = {row0, row1, row2};
    int cols[3] = {wm, w, wp};

    float pc[K_][9];
#pragma unroll
    for (int k = 0; k < K_; ++k) {
        const float* sp = S + (((size_t)b * K_ + k) << 14);
        float p[9];
        float m = 0.f;
#pragma unroll
        for (int i = 0; i < 3; ++i)
#pragma unroll
            for (int j = 0; j < 3; ++j) {
                float v = sp[rows[i] + cols[j]];
                p[i * 3 + j] = v;
                m += v;
            }
        m *= (1.f / 9.f);
#pragma unroll
        for (int n = 0; n < 9; ++n) pc[k][n] = p[n] - m;
    }

    // A = 0.9*R + (0.1*tr(R)/K + delta)*I + diag(sig2); R[i][j] = pc_i·pc_j / 9
    float A[K_][K_];
    float tr = 0.f;
#pragma unroll
    for (int i = 0; i < K_; ++i) {
        float s = 0.f;
#pragma unroll
        for (int n = 0; n < 9; ++n) s = fmaf(pc[i][n], pc[i][n], s);
        s *= (1.f / 9.f);
        tr += s;
        A[i][i] = s;
    }
#pragma unroll
    for (int i = 0; i < K_; ++i)
#pragma unroll
        for (int j = 0; j < i; ++j) {
            float s = 0.f;
#pragma unroll
            for (int n = 0; n < 9; ++n) s = fmaf(pc[i][n], pc[j][n], s);
            A[i][j] = (1.f - COV_SHRINK) * s * (1.f / 9.f);
        }
    float dl = COV_SHRINK * tr * (1.f / (float)K_) + COV_DELTA;
#pragma unroll
    for (int i = 0; i < K_; ++i)
        A[i][i] = (1.f - COV_SHRINK) * A[i][i] + dl + sig2[i];

    // Cholesky A = L L^T (L overwrites lower triangle of A)
#pragma unroll
    for (int j = 0; j < K_; ++j) {
        float d = A[j][j];
#pragma unroll
        for (int t = 0; t < j; ++t) d = fmaf(-A[j][t], A[j][t], d);
        d = sqrtf(d);
        A[j][j] = d;
        float inv = 1.f / d;
#pragma unroll
        for (int i = j + 1; i < K_; ++i) {
            float s = A[i][j];
#pragma unroll
            for (int t = 0; t < j; ++t) s = fmaf(-A[i][t], A[j][t], s);
            A[i][j] = s * inv;
        }
    }
    // forward solve L z = a0
    float z[K_];
#pragma unroll
    for (int i = 0; i < K_; ++i) {
        float s = a0[i];
#pragma unroll
        for (int t = 0; t < i; ++t) s = fmaf(-A[i][t], z[t], s);
        z[i] = s / A[i][i];
    }
    // back solve L^T x = z
    float x[K_];
#pragma unroll
    for (int i = K_ - 1; i >= 0; --i) {
        float s = z[i];
#pragma unroll
        for (int t = i + 1; t < K_; ++t) s = fmaf(-A[t][i], x[t], s);
        x[i] = s / A[i][i];
    }
    float denom = 0.f;
#pragma unroll
    for (int k = 0; k < K_; ++k) denom = fmaf(x[k], a0[k], denom);
    float invd = 1.f / denom;

    float4 o0 = make_float4(x[0] * invd, x[1] * invd, x[2] * invd, x[3] * invd);
    float4 o1 = make_float4(x[4] * invd, x[5] * invd, x[6] * invd, x[7] * invd);
    float4* dst = (float4*)(wOut + (size_t)idx * K_);
    dst[0] = o0;
    dst[1] = o1;
}

// ---------------------------------------------------------------------------
// Kernel 3: weighted fusion. One thread per output element (b,c,h,w).
// Y[b,c,h,w] = sum_k w[b,h,w,k] * X[b,k,c,h,w]
// ---------------------------------------------------------------------------
__global__ void __launch_bounds__(256)
fuse_kernel(const float* __restrict__ X,
            const float* __restrict__ wW,   // [B*HW][8]
            float* __restrict__ out) {
    int idx = blockIdx.x * blockDim.x + threadIdx.x;  // 0 .. B*C*HW-1
    int hw = idx & (HW_ - 1);
    int bc = idx >> 14;
    int b = bc >> 6;
    int c = bc & (C_ - 1);
    size_t pix = ((size_t)b << 14) + hw;

    const float4* wv4 = (const float4*)(wW + pix * K_);
    float4 wa = wv4[0];
    float4 wb = wv4[1];

    const float* xp = X + (((size_t)b * K_) * C_ + c) * HW_ + hw;
    const size_t kstride = (size_t)C_ * HW_;

    float acc;
    acc = wa.x * xp[0];
    acc = fmaf(wa.y, xp[kstride * 1], acc);
    acc = fmaf(wa.z, xp[kstride * 2], acc);
    acc = fmaf(wa.w, xp[kstride * 3], acc);
    acc = fmaf(wb.x, xp[kstride * 4], acc);
    acc = fmaf(wb.y, xp[kstride * 5], acc);
    acc = fmaf(wb.z, xp[kstride * 6], acc);
    acc = fmaf(wb.w, xp[kstride * 7], acc);
    out[idx] = acc;
}

// ---------------------------------------------------------------------------
extern "C" void kernel_launch(void* const* d_in, const int* in_sizes, int n_in,
                              void* d_out, int out_size, void* d_ws, size_t ws_size,
                              hipStream_t stream) {
    const float* X         = (const float*)d_in[0];
    const float* w1        = (const float*)d_in[1];
    const float* bn_scale  = (const float*)d_in[2];
    const float* bn_bias   = (const float*)d_in[3];
    const float* bn_mean   = (const float*)d_in[4];
    const float* bn_var    = (const float*)d_in[5];
    const float* w2        = (const float*)d_in[6];
    const float* a0_raw    = (const float*)d_in[7];
    const float* sigma_raw = (const float*)d_in[8];
    float* out = (float*)d_out;
    float* ws  = (float*)d_ws;

    float* par = ws;                       // 4096 floats (params)
    float* S   = ws + 4096;                // B*K*HW = 262144 floats
    float* wW  = ws + 4096 + (B_ * K_ * HW_);  // B*HW*K = 262144 floats

    prep_kernel<<<1, 256, 0, stream>>>(w1, bn_scale, bn_bias, bn_mean, bn_var,
                                       w2, a0_raw, sigma_raw, par);

    int n1 = B_ * K_ * HW_;                // 262144
    stage1_kernel<<<n1 / 256, 256, 0, stream>>>(X, par, par + 2048, par + 2080, S);

    int n2 = B_ * HW_;                     // 32768
    capon_kernel<<<n2 / 256, 256, 0, stream>>>(S, par + 2112, par + 2120, wW);

    int n3 = B_ * C_ * HW_;                // 2097152
    fuse_kernel<<<n3 / 256, 256, 0, stream>>>(X, wW, out);
}